// Round 1
// baseline (2613.800 us; speedup 1.0000x reference)
//
#include <hip/hip_runtime.h>
#include <hip/hip_bf16.h>
#include <cstdint>
#include <cstddef>

#define TK 8192
#define DIM 1024
#define HID 4096
#define NE 8

#define BM 128
#define BN 128
#define BK 64

typedef __attribute__((ext_vector_type(8))) __bf16 bfrag;   // 8 bf16 = 4 VGPR (MFMA A/B operand)
typedef __attribute__((ext_vector_type(4))) float ffrag;    // MFMA C/D operand

static __device__ __forceinline__ ushort f2bf(float f) {
    union { float f; uint32_t u; } v; v.f = f;
    uint32_t r = (v.u + 0x7fffu + ((v.u >> 16) & 1u)) >> 16;   // RNE, finite inputs only
    return (ushort)r;
}

static __device__ __forceinline__ uint4 pack8(float4 a, float4 b) {
    union { ushort u[8]; uint4 q; } pk;
    pk.u[0] = f2bf(a.x); pk.u[1] = f2bf(a.y); pk.u[2] = f2bf(a.z); pk.u[3] = f2bf(a.w);
    pk.u[4] = f2bf(b.x); pk.u[5] = f2bf(b.y); pk.u[6] = f2bf(b.z); pk.u[7] = f2bf(b.w);
    return pk.q;
}

// LDS chunk addressing: tile is [128 rows][8 chunks of 8 bf16]; XOR-swizzle chunks within row
#define LDSIDX(r, kc) ((((r) << 3) + ((kc) ^ ((r) & 7))) << 3)

// ---------------- router: f64-accurate logits, top-2, renormalized weights ----------------
__global__ __launch_bounds__(256) void k_router(const float* __restrict__ x,
                                                const float* __restrict__ gw,
                                                int* __restrict__ topi, float* __restrict__ topw) {
    int t = blockIdx.x * 4 + (threadIdx.x >> 6);
    int lane = threadIdx.x & 63;
    if (t >= TK) return;
    double acc[NE];
#pragma unroll
    for (int e = 0; e < NE; ++e) acc[e] = 0.0;
    const float* xr = x + (size_t)t * DIM;
    for (int k = lane; k < DIM; k += 64) {
        double xv = (double)xr[k];
#pragma unroll
        for (int e = 0; e < NE; ++e) acc[e] += xv * (double)gw[e * DIM + k];
    }
#pragma unroll
    for (int e = 0; e < NE; ++e) {
#pragma unroll
        for (int off = 32; off > 0; off >>= 1) acc[e] += __shfl_xor(acc[e], off);
    }
    if (lane == 0) {
        int i1 = 0;
#pragma unroll
        for (int e = 1; e < NE; ++e) if (acc[e] > acc[i1]) i1 = e;
        int i2 = (i1 == 0) ? 1 : 0;
#pragma unroll
        for (int e = 0; e < NE; ++e) if (e != i1 && acc[e] > acc[i2]) i2 = e;
        double w = 1.0 / (1.0 + exp(acc[i2] - acc[i1]));   // = p1/(p1+p2), Z cancels
        topi[t * 2 + 0] = i1; topi[t * 2 + 1] = i2;
        topw[t * 2 + 0] = (float)w; topw[t * 2 + 1] = (float)(1.0 - w);
    }
}

__global__ void k_count(const int* __restrict__ topi, int* __restrict__ counts) {
    int i = blockIdx.x * blockDim.x + threadIdx.x;
    if (i < 2 * TK) atomicAdd(&counts[topi[i]], 1);
}

__global__ void k_scan(const int* __restrict__ counts, int* __restrict__ offs, int* __restrict__ cursor) {
    if (threadIdx.x == 0 && blockIdx.x == 0) {
        int s = 0;
        for (int e = 0; e < NE; ++e) { offs[e] = s; cursor[e] = s; s += counts[e]; }
        offs[NE] = s;
    }
}

__global__ void k_scatter(const int* __restrict__ topi, const float* __restrict__ topw,
                          int* __restrict__ cursor, int* __restrict__ perm, float* __restrict__ pw) {
    int t = blockIdx.x * blockDim.x + threadIdx.x;
    if (t >= TK) return;
#pragma unroll
    for (int k = 0; k < 2; ++k) {
        int e = topi[t * 2 + k];
        int pos = atomicAdd(&cursor[e], 1);
        perm[pos] = t; pw[pos] = topw[t * 2 + k];
    }
}

// ---------------- GEMM A: H[pos,n] = silu(x@w1^T) * (x@w3^T), bf16 out ----------------
__global__ __launch_bounds__(256) void k_ffn1(const float* __restrict__ x,
                                              const float* __restrict__ w1,
                                              const float* __restrict__ w3,
                                              const int* __restrict__ offs,
                                              const int* __restrict__ perm,
                                              ushort* __restrict__ H) {
    const int mt = blockIdx.x, nt = blockIdx.y, e = blockIdx.z;
    const int off = offs[e], end = offs[e + 1];
    const int m0 = off + mt * BM;
    if (m0 >= end) return;
    const int nrows = min(BM, end - m0);

    __shared__ ushort lA[BM * BK];
    __shared__ ushort lB1[BN * BK];
    __shared__ ushort lB3[BN * BK];
    __shared__ int lTok[BM];

    const int tid = threadIdx.x;
    if (tid < BM) lTok[tid] = (tid < nrows) ? perm[m0 + tid] : -1;
    __syncthreads();

    const int lane = tid & 63, wid = tid >> 6;
    const int wm = (wid >> 1) * 64, wn = (wid & 1) * 64;

    ffrag acc1[4][4], acc3[4][4];
#pragma unroll
    for (int i = 0; i < 4; ++i)
#pragma unroll
        for (int j = 0; j < 4; ++j) { acc1[i][j] = (ffrag)0.f; acc3[i][j] = (ffrag)0.f; }

    const float* w1e = w1 + (size_t)e * HID * DIM + (size_t)nt * BN * DIM;
    const float* w3e = w3 + (size_t)e * HID * DIM + (size_t)nt * BN * DIM;

    for (int k0 = 0; k0 < DIM; k0 += BK) {
#pragma unroll
        for (int c = 0; c < 4; ++c) {
            int ci = tid + c * 256;              // 0..1023 : r=ci>>3 (row), kc=ci&7 (8-elem chunk)
            int r = ci >> 3, kc = ci & 7;
            int dst = LDSIDX(r, kc);
            {   // X (gathered rows, f32 -> bf16)
                int tok = lTok[r];
                float4 v0 = make_float4(0.f, 0.f, 0.f, 0.f), v1 = v0;
                if (tok >= 0) {
                    const float* p = x + (size_t)tok * DIM + k0 + kc * 8;
                    v0 = *(const float4*)p; v1 = *(const float4*)(p + 4);
                }
                *(uint4*)&lA[dst] = pack8(v0, v1);
            }
            {   // W1 row (hidden index nt*BN + r)
                const float* p = w1e + (size_t)r * DIM + k0 + kc * 8;
                *(uint4*)&lB1[dst] = pack8(*(const float4*)p, *(const float4*)(p + 4));
            }
            {   // W3 row
                const float* p = w3e + (size_t)r * DIM + k0 + kc * 8;
                *(uint4*)&lB3[dst] = pack8(*(const float4*)p, *(const float4*)(p + 4));
            }
        }
        __syncthreads();
#pragma unroll
        for (int s = 0; s < 2; ++s) {
            bfrag a[4], b1[4], b3[4];
            const int kc = s * 4 + (lane >> 4);
#pragma unroll
            for (int i = 0; i < 4; ++i) {
                int r = wm + i * 16 + (lane & 15);
                a[i] = *(const bfrag*)&lA[LDSIDX(r, kc)];
            }
#pragma unroll
            for (int j = 0; j < 4; ++j) {
                int r = wn + j * 16 + (lane & 15);
                b1[j] = *(const bfrag*)&lB1[LDSIDX(r, kc)];
                b3[j] = *(const bfrag*)&lB3[LDSIDX(r, kc)];
            }
#pragma unroll
            for (int i = 0; i < 4; ++i)
#pragma unroll
                for (int j = 0; j < 4; ++j) {
                    acc1[i][j] = __builtin_amdgcn_mfma_f32_16x16x32_bf16(a[i], b1[j], acc1[i][j], 0, 0, 0);
                    acc3[i][j] = __builtin_amdgcn_mfma_f32_16x16x32_bf16(a[i], b3[j], acc3[i][j], 0, 0, 0);
                }
        }
        __syncthreads();
    }

    // epilogue: silu(h1)*h3 -> bf16 H.  C/D layout: col = lane&15, row = (lane>>4)*4 + q
    const int colbase = nt * BN + wn;
#pragma unroll
    for (int i = 0; i < 4; ++i) {
        int rbase = wm + i * 16 + ((lane >> 4) << 2);
#pragma unroll
        for (int q = 0; q < 4; ++q) {
            int rl = rbase + q;
            if (rl >= nrows) continue;
            size_t rowoff = (size_t)(m0 + rl) * HID;
#pragma unroll
            for (int j = 0; j < 4; ++j) {
                int col = colbase + j * 16 + (lane & 15);
                float h1 = acc1[i][j][q], h3 = acc3[i][j][q];
                float val = (h1 / (1.f + __expf(-h1))) * h3;
                H[rowoff + col] = f2bf(val);
            }
        }
    }
}

// ---------------- GEMM B: out[tok,:] += pw[pos] * (H[pos,:] @ w2^T) ----------------
__global__ __launch_bounds__(256) void k_ffn2(const ushort* __restrict__ H,
                                              const float* __restrict__ w2,
                                              const int* __restrict__ offs,
                                              const int* __restrict__ perm,
                                              const float* __restrict__ pw,
                                              float* __restrict__ out) {
    const int mt = blockIdx.x, nt = blockIdx.y, e = blockIdx.z;
    const int off = offs[e], end = offs[e + 1];
    const int m0 = off + mt * BM;
    if (m0 >= end) return;
    const int nrows = min(BM, end - m0);

    __shared__ ushort lA[BM * BK];
    __shared__ ushort lB[BN * BK];
    __shared__ int lTok[BM];
    __shared__ float lPw[BM];

    const int tid = threadIdx.x;
    if (tid < BM) {
        bool v = tid < nrows;
        lTok[tid] = v ? perm[m0 + tid] : -1;
        lPw[tid]  = v ? pw[m0 + tid] : 0.f;
    }
    __syncthreads();

    const int lane = tid & 63, wid = tid >> 6;
    const int wm = (wid >> 1) * 64, wn = (wid & 1) * 64;

    ffrag acc[4][4];
#pragma unroll
    for (int i = 0; i < 4; ++i)
#pragma unroll
        for (int j = 0; j < 4; ++j) acc[i][j] = (ffrag)0.f;

    const float* w2e = w2 + (size_t)e * DIM * HID + (size_t)nt * BN * HID;

    for (int k0 = 0; k0 < HID; k0 += BK) {
#pragma unroll
        for (int c = 0; c < 4; ++c) {
            int ci = tid + c * 256;
            int r = ci >> 3, kc = ci & 7;
            int dst = LDSIDX(r, kc);
            {   // H tile (already bf16; clamped read is always a valid H row)
                int pos = min(m0 + r, 2 * TK - 1);
                *(uint4*)&lA[dst] = *(const uint4*)&H[(size_t)pos * HID + k0 + kc * 8];
            }
            {   // W2 row (f32 -> bf16)
                const float* p = w2e + (size_t)r * HID + k0 + kc * 8;
                *(uint4*)&lB[dst] = pack8(*(const float4*)p, *(const float4*)(p + 4));
            }
        }
        __syncthreads();
#pragma unroll
        for (int s = 0; s < 2; ++s) {
            bfrag a[4], b[4];
            const int kc = s * 4 + (lane >> 4);
#pragma unroll
            for (int i = 0; i < 4; ++i) {
                int r = wm + i * 16 + (lane & 15);
                a[i] = *(const bfrag*)&lA[LDSIDX(r, kc)];
            }
#pragma unroll
            for (int j = 0; j < 4; ++j) {
                int r = wn + j * 16 + (lane & 15);
                b[j] = *(const bfrag*)&lB[LDSIDX(r, kc)];
            }
#pragma unroll
            for (int i = 0; i < 4; ++i)
#pragma unroll
                for (int j = 0; j < 4; ++j)
                    acc[i][j] = __builtin_amdgcn_mfma_f32_16x16x32_bf16(a[i], b[j], acc[i][j], 0, 0, 0);
        }
        __syncthreads();
    }

    const int colbase = nt * BN + wn;
#pragma unroll
    for (int i = 0; i < 4; ++i) {
        int rbase = wm + i * 16 + ((lane >> 4) << 2);
#pragma unroll
        for (int q = 0; q < 4; ++q) {
            int rl = rbase + q;
            if (rl >= nrows) continue;
            int tok = lTok[rl];
            float w = lPw[rl];
            if (tok < 0) continue;
            size_t rowoff = (size_t)tok * DIM;
#pragma unroll
            for (int j = 0; j < 4; ++j) {
                int col = colbase + j * 16 + (lane & 15);
                atomicAdd(&out[rowoff + col], acc[i][j][q] * w);   // exactly 2 adds/elem, commutative => deterministic
            }
        }
    }
}

extern "C" void kernel_launch(void* const* d_in, const int* in_sizes, int n_in,
                              void* d_out, int out_size, void* d_ws, size_t ws_size,
                              hipStream_t stream) {
    const float* x  = (const float*)d_in[0];
    const float* gw = (const float*)d_in[1];
    const float* w1 = (const float*)d_in[2];
    const float* w2 = (const float*)d_in[3];   // dict order: x, gate_w, w1, w2, w3 !
    const float* w3 = (const float*)d_in[4];
    float* out = (float*)d_out;

    char* ws = (char*)d_ws;
    int*    topi   = (int*)(ws + 0);             // 64 KB
    float*  topw   = (float*)(ws + 65536);       // 64 KB
    int*    perm   = (int*)(ws + 131072);        // 64 KB
    float*  pw     = (float*)(ws + 196608);      // 64 KB
    int*    counts = (int*)(ws + 262144);        // 32 B
    int*    offs   = (int*)(ws + 262144 + 256);  // 36 B
    int*    cursor = (int*)(ws + 262144 + 512);  // 32 B
    ushort* H      = (ushort*)(ws + 524288);     // 16384 x 4096 bf16 = 128 MiB

    hipMemsetAsync(counts, 0, 32, stream);
    hipMemsetAsync(out, 0, (size_t)out_size * sizeof(float), stream);

    k_router<<<dim3(TK / 4), 256, 0, stream>>>(x, gw, topi, topw);
    k_count<<<dim3((2 * TK) / 256), 256, 0, stream>>>(topi, counts);
    k_scan<<<dim3(1), 64, 0, stream>>>(counts, offs, cursor);
    k_scatter<<<dim3(TK / 256), 256, 0, stream>>>(topi, topw, cursor, perm, pw);

    // grids sized for worst case (all 8192 tokens on one expert); empty tiles early-exit
    k_ffn1<<<dim3(TK / BM, HID / BN, NE), 256, 0, stream>>>(x, w1, w3, offs, perm, H);
    k_ffn2<<<dim3(TK / BM, DIM / BN, NE), 256, 0, stream>>>(H, w2, offs, perm, pw, out);
}

// Round 2
// 1697.069 us; speedup vs baseline: 1.5402x; 1.5402x over previous
//
#include <hip/hip_runtime.h>
#include <hip/hip_bf16.h>
#include <cstdint>
#include <cstddef>

#define TK 8192
#define DIM 1024
#define HID 4096
#define NE 8

#define BM 128
#define BN 128
#define BK 64

typedef __attribute__((ext_vector_type(8))) __bf16 bfrag;   // 8 bf16 = 4 VGPR (MFMA A/B operand)
typedef __attribute__((ext_vector_type(4))) float ffrag;    // MFMA C/D operand

static __device__ __forceinline__ ushort f2bf(float f) {
    union { float f; uint32_t u; } v; v.f = f;
    uint32_t r = (v.u + 0x7fffu + ((v.u >> 16) & 1u)) >> 16;   // RNE, finite inputs only
    return (ushort)r;
}

static __device__ __forceinline__ uint4 pack8(float4 a, float4 b) {
    union { ushort u[8]; uint4 q; } pk;
    pk.u[0] = f2bf(a.x); pk.u[1] = f2bf(a.y); pk.u[2] = f2bf(a.z); pk.u[3] = f2bf(a.w);
    pk.u[4] = f2bf(b.x); pk.u[5] = f2bf(b.y); pk.u[6] = f2bf(b.z); pk.u[7] = f2bf(b.w);
    return pk.q;
}

// async global->LDS, 16B per lane; LDS dest = wave-uniform base + lane*16 (m97/m104 semantics)
static __device__ __forceinline__ void gld16(const ushort* g, ushort* l) {
    __builtin_amdgcn_global_load_lds(
        (const __attribute__((address_space(1))) unsigned int*)g,
        (__attribute__((address_space(3))) unsigned int*)l, 16, 0, 0);
}

// LDS chunk addressing: tile is [128 rows][8 chunks of 8 bf16]; XOR-swizzle chunks within row.
// Index in ushorts. Chunk slot s stores source chunk kc = (s&7)^(r&7) of row r = s>>3.
#define LDSIDX(r, kc) ((((r) << 3) + ((kc) ^ ((r) & 7))) << 3)

// ---------------- f32 -> bf16 streaming convert (8 elems/thread) ----------------
__global__ __launch_bounds__(256) void k_cvt(const float* __restrict__ src,
                                             ushort* __restrict__ dst, int n8) {
    int i = blockIdx.x * blockDim.x + threadIdx.x;
    if (i >= n8) return;
    const float4* p = (const float4*)src + (size_t)i * 2;
    ((uint4*)dst)[i] = pack8(p[0], p[1]);
}

// ---------------- router: f64-accurate logits, top-2, renormalized weights ----------------
__global__ __launch_bounds__(256) void k_router(const float* __restrict__ x,
                                                const float* __restrict__ gw,
                                                int* __restrict__ topi, float* __restrict__ topw) {
    int t = blockIdx.x * 4 + (threadIdx.x >> 6);
    int lane = threadIdx.x & 63;
    if (t >= TK) return;
    double acc[NE];
#pragma unroll
    for (int e = 0; e < NE; ++e) acc[e] = 0.0;
    const float* xr = x + (size_t)t * DIM;
    for (int k = lane; k < DIM; k += 64) {
        double xv = (double)xr[k];
#pragma unroll
        for (int e = 0; e < NE; ++e) acc[e] += xv * (double)gw[e * DIM + k];
    }
#pragma unroll
    for (int e = 0; e < NE; ++e) {
#pragma unroll
        for (int off = 32; off > 0; off >>= 1) acc[e] += __shfl_xor(acc[e], off);
    }
    if (lane == 0) {
        int i1 = 0;
#pragma unroll
        for (int e = 1; e < NE; ++e) if (acc[e] > acc[i1]) i1 = e;
        int i2 = (i1 == 0) ? 1 : 0;
#pragma unroll
        for (int e = 0; e < NE; ++e) if (e != i1 && acc[e] > acc[i2]) i2 = e;
        double w = 1.0 / (1.0 + exp(acc[i2] - acc[i1]));   // = p1/(p1+p2), Z cancels
        topi[t * 2 + 0] = i1; topi[t * 2 + 1] = i2;
        topw[t * 2 + 0] = (float)w; topw[t * 2 + 1] = (float)(1.0 - w);
    }
}

__global__ void k_count(const int* __restrict__ topi, int* __restrict__ counts) {
    int i = blockIdx.x * blockDim.x + threadIdx.x;
    if (i < 2 * TK) atomicAdd(&counts[topi[i]], 1);
}

__global__ void k_scan(const int* __restrict__ counts, int* __restrict__ offs, int* __restrict__ cursor) {
    if (threadIdx.x == 0 && blockIdx.x == 0) {
        int s = 0;
        for (int e = 0; e < NE; ++e) { offs[e] = s; cursor[e] = s; s += counts[e]; }
        offs[NE] = s;
    }
}

__global__ void k_scatter(const int* __restrict__ topi, const float* __restrict__ topw,
                          int* __restrict__ cursor, int* __restrict__ perm, float* __restrict__ pw) {
    int t = blockIdx.x * blockDim.x + threadIdx.x;
    if (t >= TK) return;
#pragma unroll
    for (int k = 0; k < 2; ++k) {
        int e = topi[t * 2 + k];
        int pos = atomicAdd(&cursor[e], 1);
        perm[pos] = t; pw[pos] = topw[t * 2 + k];
    }
}

// ---------------- GEMM A: H[pos,n] = silu(x@w1^T) * (x@w3^T), bf16 out ----------------
template <bool PRE>
__global__ __launch_bounds__(256) void k_ffn1(const float* __restrict__ xf,
                                              const float* __restrict__ w1f,
                                              const float* __restrict__ w3f,
                                              const ushort* __restrict__ xb,
                                              const ushort* __restrict__ w1b,
                                              const ushort* __restrict__ w3b,
                                              const int* __restrict__ offs,
                                              const int* __restrict__ perm,
                                              ushort* __restrict__ H) {
    const int mt = blockIdx.x, nt = blockIdx.y, e = blockIdx.z;
    const int off = offs[e], end = offs[e + 1];
    const int m0 = off + mt * BM;
    if (m0 >= end) return;
    const int nrows = min(BM, end - m0);

    __shared__ ushort lA[BM * BK];
    __shared__ ushort lB1[BN * BK];
    __shared__ ushort lB3[BN * BK];
    __shared__ int lTok[BM];

    const int tid = threadIdx.x;
    if (tid < BM) lTok[tid] = (tid < nrows) ? perm[m0 + tid] : -1;
    __syncthreads();

    const int lane = tid & 63, wid = tid >> 6;
    const int wm = (wid >> 1) * 64, wn = (wid & 1) * 64;

    ffrag acc1[4][4], acc3[4][4];
#pragma unroll
    for (int i = 0; i < 4; ++i)
#pragma unroll
        for (int j = 0; j < 4; ++j) { acc1[i][j] = (ffrag)0.f; acc3[i][j] = (ffrag)0.f; }

    // precomputed per-lane source pointers for async staging (PRE path)
    const ushort* pA[4]; const ushort* pB1[4]; const ushort* pB3[4];
    if constexpr (PRE) {
        const ushort* w1e = w1b + (size_t)e * HID * DIM + (size_t)nt * BN * DIM;
        const ushort* w3e = w3b + (size_t)e * HID * DIM + (size_t)nt * BN * DIM;
#pragma unroll
        for (int i = 0; i < 4; ++i) {
            int s = i * 256 + tid;               // linear 16B chunk slot in LDS tile
            int r = s >> 3;
            int kc = (s & 7) ^ (r & 7);          // inverse-swizzled source chunk
            int tok = lTok[r]; if (tok < 0) tok = 0;   // pad rows: any finite data, results discarded
            pA[i]  = xb  + (size_t)tok * DIM + kc * 8;
            pB1[i] = w1e + (size_t)r * DIM + kc * 8;
            pB3[i] = w3e + (size_t)r * DIM + kc * 8;
        }
    }
    const float* w1fe = w1f + (size_t)e * HID * DIM + (size_t)nt * BN * DIM;
    const float* w3fe = w3f + (size_t)e * HID * DIM + (size_t)nt * BN * DIM;

    for (int k0 = 0; k0 < DIM; k0 += BK) {
        if constexpr (PRE) {
#pragma unroll
            for (int i = 0; i < 4; ++i) {
                const int ldso = (i * 256 + wid * 64) * 8;   // wave-uniform base (ushorts)
                gld16(pA[i]  + k0, &lA[ldso]);
                gld16(pB1[i] + k0, &lB1[ldso]);
                gld16(pB3[i] + k0, &lB3[ldso]);
            }
        } else {
#pragma unroll
            for (int c = 0; c < 4; ++c) {
                int ci = tid + c * 256;
                int r = ci >> 3, kc = ci & 7;
                int dst = LDSIDX(r, kc);
                {
                    int tok = lTok[r];
                    float4 v0 = make_float4(0.f, 0.f, 0.f, 0.f), v1 = v0;
                    if (tok >= 0) {
                        const float* p = xf + (size_t)tok * DIM + k0 + kc * 8;
                        v0 = *(const float4*)p; v1 = *(const float4*)(p + 4);
                    }
                    *(uint4*)&lA[dst] = pack8(v0, v1);
                }
                {
                    const float* p = w1fe + (size_t)r * DIM + k0 + kc * 8;
                    *(uint4*)&lB1[dst] = pack8(*(const float4*)p, *(const float4*)(p + 4));
                }
                {
                    const float* p = w3fe + (size_t)r * DIM + k0 + kc * 8;
                    *(uint4*)&lB3[dst] = pack8(*(const float4*)p, *(const float4*)(p + 4));
                }
            }
        }
        __syncthreads();
#pragma unroll
        for (int s = 0; s < 2; ++s) {
            bfrag a[4], b1[4], b3[4];
            const int kc = s * 4 + (lane >> 4);
#pragma unroll
            for (int i = 0; i < 4; ++i) {
                int r = wm + i * 16 + (lane & 15);
                a[i] = *(const bfrag*)&lA[LDSIDX(r, kc)];
            }
#pragma unroll
            for (int j = 0; j < 4; ++j) {
                int r = wn + j * 16 + (lane & 15);
                b1[j] = *(const bfrag*)&lB1[LDSIDX(r, kc)];
                b3[j] = *(const bfrag*)&lB3[LDSIDX(r, kc)];
            }
#pragma unroll
            for (int i = 0; i < 4; ++i)
#pragma unroll
                for (int j = 0; j < 4; ++j) {
                    acc1[i][j] = __builtin_amdgcn_mfma_f32_16x16x32_bf16(a[i], b1[j], acc1[i][j], 0, 0, 0);
                    acc3[i][j] = __builtin_amdgcn_mfma_f32_16x16x32_bf16(a[i], b3[j], acc3[i][j], 0, 0, 0);
                }
        }
        __syncthreads();
    }

    // epilogue: silu(h1)*h3 -> bf16 H.  C/D layout: col = lane&15, row = (lane>>4)*4 + q
    const int colbase = nt * BN + wn;
#pragma unroll
    for (int i = 0; i < 4; ++i) {
        int rbase = wm + i * 16 + ((lane >> 4) << 2);
#pragma unroll
        for (int q = 0; q < 4; ++q) {
            int rl = rbase + q;
            if (rl >= nrows) continue;
            size_t rowoff = (size_t)(m0 + rl) * HID;
#pragma unroll
            for (int j = 0; j < 4; ++j) {
                int col = colbase + j * 16 + (lane & 15);
                float h1 = acc1[i][j][q], h3 = acc3[i][j][q];
                float val = (h1 / (1.f + __expf(-h1))) * h3;
                H[rowoff + col] = f2bf(val);
            }
        }
    }
}

// ---------------- GEMM B: out[tok,:] += pw[pos] * (H[pos,:] @ w2^T) ----------------
template <bool PRE>
__global__ __launch_bounds__(256) void k_ffn2(const ushort* __restrict__ H,
                                              const float* __restrict__ w2f,
                                              const ushort* __restrict__ w2b,
                                              const int* __restrict__ offs,
                                              const int* __restrict__ perm,
                                              const float* __restrict__ pw,
                                              float* __restrict__ out) {
    const int mt = blockIdx.x, nt = blockIdx.y, e = blockIdx.z;
    const int off = offs[e], end = offs[e + 1];
    const int m0 = off + mt * BM;
    if (m0 >= end) return;
    const int nrows = min(BM, end - m0);

    __shared__ ushort lA[BM * BK];
    __shared__ ushort lB[BN * BK];
    __shared__ int lTok[BM];
    __shared__ float lPw[BM];

    const int tid = threadIdx.x;
    if (tid < BM) {
        bool v = tid < nrows;
        lTok[tid] = v ? perm[m0 + tid] : -1;
        lPw[tid]  = v ? pw[m0 + tid] : 0.f;
    }
    __syncthreads();

    const int lane = tid & 63, wid = tid >> 6;
    const int wm = (wid >> 1) * 64, wn = (wid & 1) * 64;

    ffrag acc[4][4];
#pragma unroll
    for (int i = 0; i < 4; ++i)
#pragma unroll
        for (int j = 0; j < 4; ++j) acc[i][j] = (ffrag)0.f;

    const ushort* pA[4]; const ushort* pB[4];
    if constexpr (PRE) {
        const ushort* w2e = w2b + (size_t)e * DIM * HID + (size_t)nt * BN * HID;
#pragma unroll
        for (int i = 0; i < 4; ++i) {
            int s = i * 256 + tid;
            int r = s >> 3;
            int kc = (s & 7) ^ (r & 7);
            int pos = m0 + r; if (pos > 2 * TK - 1) pos = 2 * TK - 1;   // clamp into H
            pA[i] = H   + (size_t)pos * HID + kc * 8;
            pB[i] = w2e + (size_t)r * HID + kc * 8;
        }
    }
    const float* w2fe = w2f + (size_t)e * DIM * HID + (size_t)nt * BN * HID;

    for (int k0 = 0; k0 < HID; k0 += BK) {
        if constexpr (PRE) {
#pragma unroll
            for (int i = 0; i < 4; ++i) {
                const int ldso = (i * 256 + wid * 64) * 8;
                gld16(pA[i] + k0, &lA[ldso]);
                gld16(pB[i] + k0, &lB[ldso]);
            }
        } else {
#pragma unroll
            for (int c = 0; c < 4; ++c) {
                int ci = tid + c * 256;
                int r = ci >> 3, kc = ci & 7;
                int dst = LDSIDX(r, kc);
                {
                    int pos = min(m0 + r, 2 * TK - 1);
                    *(uint4*)&lA[dst] = *(const uint4*)&H[(size_t)pos * HID + k0 + kc * 8];
                }
                {
                    const float* p = w2fe + (size_t)r * HID + k0 + kc * 8;
                    *(uint4*)&lB[dst] = pack8(*(const float4*)p, *(const float4*)(p + 4));
                }
            }
        }
        __syncthreads();
#pragma unroll
        for (int s = 0; s < 2; ++s) {
            bfrag a[4], b[4];
            const int kc = s * 4 + (lane >> 4);
#pragma unroll
            for (int i = 0; i < 4; ++i) {
                int r = wm + i * 16 + (lane & 15);
                a[i] = *(const bfrag*)&lA[LDSIDX(r, kc)];
            }
#pragma unroll
            for (int j = 0; j < 4; ++j) {
                int r = wn + j * 16 + (lane & 15);
                b[j] = *(const bfrag*)&lB[LDSIDX(r, kc)];
            }
#pragma unroll
            for (int i = 0; i < 4; ++i)
#pragma unroll
                for (int j = 0; j < 4; ++j)
                    acc[i][j] = __builtin_amdgcn_mfma_f32_16x16x32_bf16(a[i], b[j], acc[i][j], 0, 0, 0);
        }
        __syncthreads();
    }

    const int colbase = nt * BN + wn;
#pragma unroll
    for (int i = 0; i < 4; ++i) {
        int rbase = wm + i * 16 + ((lane >> 4) << 2);
#pragma unroll
        for (int q = 0; q < 4; ++q) {
            int rl = rbase + q;
            if (rl >= nrows) continue;
            int tok = lTok[rl];
            float w = lPw[rl];
            if (tok < 0) continue;
            size_t rowoff = (size_t)tok * DIM;
#pragma unroll
            for (int j = 0; j < 4; ++j) {
                int col = colbase + j * 16 + (lane & 15);
                atomicAdd(&out[rowoff + col], acc[i][j][q] * w);   // exactly 2 adds/elem, commutative => deterministic
            }
        }
    }
}

extern "C" void kernel_launch(void* const* d_in, const int* in_sizes, int n_in,
                              void* d_out, int out_size, void* d_ws, size_t ws_size,
                              hipStream_t stream) {
    const float* x  = (const float*)d_in[0];
    const float* gw = (const float*)d_in[1];
    const float* w1 = (const float*)d_in[2];
    const float* w2 = (const float*)d_in[3];   // dict order: x, gate_w, w1, w2, w3 !
    const float* w3 = (const float*)d_in[4];
    float* out = (float*)d_out;

    char* ws = (char*)d_ws;
    int*    topi   = (int*)(ws + 0);             // 64 KB
    float*  topw   = (float*)(ws + 65536);       // 64 KB
    int*    perm   = (int*)(ws + 131072);        // 64 KB
    float*  pw     = (float*)(ws + 196608);      // 64 KB
    int*    counts = (int*)(ws + 262144);
    int*    offs   = (int*)(ws + 262144 + 256);
    int*    cursor = (int*)(ws + 262144 + 512);

    const size_t OFF_XB = 524288;                       // xb: 16 MiB
    const size_t OFF_H  = OFF_XB + 16777216;            // H : 128 MiB
    const size_t OFF_WA = OFF_H + 134217728;            // w1b, later w2b: 64 MiB
    const size_t OFF_WB = OFF_WA + 67108864;            // w3b: 64 MiB
    const size_t NEED   = OFF_WB + 67108864;            // 272.5 MiB total

    hipMemsetAsync(counts, 0, 32, stream);
    hipMemsetAsync(out, 0, (size_t)out_size * sizeof(float), stream);

    k_router<<<dim3(TK / 4), 256, 0, stream>>>(x, gw, topi, topw);
    k_count<<<dim3((2 * TK) / 256), 256, 0, stream>>>(topi, counts);
    k_scan<<<dim3(1), 64, 0, stream>>>(counts, offs, cursor);
    k_scatter<<<dim3(TK / 256), 256, 0, stream>>>(topi, topw, cursor, perm, pw);

    if (ws_size >= NEED) {
        ushort* xb  = (ushort*)(ws + OFF_XB);
        ushort* H   = (ushort*)(ws + OFF_H);
        ushort* wA  = (ushort*)(ws + OFF_WA);
        ushort* wB  = (ushort*)(ws + OFF_WB);

        k_cvt<<<dim3((TK * DIM / 8) / 256), 256, 0, stream>>>(x, xb, TK * DIM / 8);
        k_cvt<<<dim3((NE * HID * DIM / 8) / 256), 256, 0, stream>>>(w1, wA, NE * HID * DIM / 8);
        k_cvt<<<dim3((NE * HID * DIM / 8) / 256), 256, 0, stream>>>(w3, wB, NE * HID * DIM / 8);

        k_ffn1<true><<<dim3(TK / BM, HID / BN, NE), 256, 0, stream>>>(
            x, w1, w3, xb, wA, wB, offs, perm, H);

        // w1b dead now; reuse its slot for w2b
        k_cvt<<<dim3((NE * DIM * HID / 8) / 256), 256, 0, stream>>>(w2, wA, NE * DIM * HID / 8);

        k_ffn2<true><<<dim3(TK / BM, DIM / BN, NE), 256, 0, stream>>>(
            H, w2, wA, offs, perm, pw, out);
    } else {
        // fallback: round-0 fused-convert path (needs only H)
        ushort* H = (ushort*)(ws + 524288);
        k_ffn1<false><<<dim3(TK / BM, HID / BN, NE), 256, 0, stream>>>(
            x, w1, w3, nullptr, nullptr, nullptr, offs, perm, H);
        k_ffn2<false><<<dim3(TK / BM, DIM / BN, NE), 256, 0, stream>>>(
            H, w2, nullptr, offs, perm, pw, out);
    }
}